// Round 6
// baseline (196.812 us; speedup 1.0000x reference)
//
#include <hip/hip_runtime.h>
#include <hip/hip_fp16.h>
#include <math.h>

// Problem constants (match reference exactly)
#define BROWS 1024
#define NPTS  32768
#define MPTS  16384          // NPTS/2 (complex FFT size via real-packing trick)
#define LOG2M 14
#define NTHR  1024
#define MIN_IDX 1092         // argmin |f - 40/60|, f[k]=k*10/16384 (exact fp32 grid)
#define MAX_IDX 6827         // argmin |f - 250/60|
#define DENOMF  5732.0f      // MAX_IDX - MIN_IDX - 3
#define W0 (-6.283185307179586f / (float)MPTS)

// LDS pad-swizzle: one element pad per 16 keeps all 4^k strides at <=2-way
// bank aliasing with 4B elements (half2): element index == bank word index.
#define PADI(i) ((i) + ((i) >> 4))
#define ZLEN    (MPTS + (MPTS >> 4))   // 17408 half2 = 68 KiB -> 2 blocks/CU

__device__ inline float2 ldz(const __half2* __restrict__ z, int i) {
    return __half22float2(z[i]);
}
__device__ inline void stz(__half2* __restrict__ z, int i, float x, float y) {
    z[i] = __floats2half2_rn(x, y);
}

// Radix-4 DIF butterfly, in-place on 4 regs; slot order (+0,+q,+2q,+3q).
// Twiddles: p1 *= (c2,s2)=W^2j, p2 *= (c1,s1)=W^j, p3 *= (c3,s3)=W^3j.
__device__ inline void bfly4(float2& p0, float2& p1, float2& p2, float2& p3,
                             float c1, float s1, float c2, float s2,
                             float c3, float s3) {
    float e0x = p0.x + p2.x, e0y = p0.y + p2.y;
    float e1x = p0.x - p2.x, e1y = p0.y - p2.y;
    float e2x = p1.x + p3.x, e2y = p1.y + p3.y;
    float e3x = p1.x - p3.x, e3y = p1.y - p3.y;
    float o1x = e0x - e2x, o1y = e0y - e2y;
    float o2x = e1x + e3y, o2y = e1y - e3x;
    float o3x = e1x - e3y, o3y = e1y + e3x;
    p0 = make_float2(e0x + e2x, e0y + e2y);
    p1 = make_float2(o1x * c2 - o1y * s2, o1x * s2 + o1y * c2);
    p2 = make_float2(o2x * c1 - o2y * s1, o2x * s1 + o2y * c1);
    p3 = make_float2(o3x * c3 - o3y * s3, o3x * s3 + o3y * c3);
}

// Fused pair of radix-4 DIF stages (global stage indices R, R+1) in registers.
// One sincos per call; other twiddles via constant rotations e^{-2pi i c/16}
// (stage R) and repeated complex squaring T^4/T^8/T^12 (stage R+1).
// FINAL additionally performs the last radix-4 stage (q=1, twiddle-free)
// across 4 adjacent lanes via shfl_xor and stores the result.
template<int R, int L2S, bool FINAL>
__device__ inline void fused16(__half2* __restrict__ z, int tid) {
    const int q2  = 1 << L2S;
    const int t   = tid & (q2 - 1);
    const int blk = tid >> L2S;
    const int i0  = (blk << (L2S + 4)) + t;

    float2 x[16];
    #pragma unroll
    for (int j = 0; j < 16; ++j) x[j] = ldz(z, PADI(i0 + (j << L2S)));

    const float A1 = W0 * (float)(1 << (2 * R));
    float ct, st;
    __sincosf(A1 * (float)t, &st, &ct);

    // Stage R: sub-butterfly c on (x[c],x[c+4],x[c+8],x[c+12]),
    // twiddle W^((c<<L2S)+t) = T * e^{-2pi i c/16}.
    {
        const float kc[4] = {1.0f, 0.9238795325f, 0.7071067812f, 0.3826834324f};
        const float ks[4] = {0.0f, -0.3826834324f, -0.7071067812f, -0.9238795325f};
        #pragma unroll
        for (int c = 0; c < 4; ++c) {
            float c1 = ct * kc[c] - st * ks[c];
            float s1 = st * kc[c] + ct * ks[c];
            float c2 = c1 * c1 - s1 * s1, s2 = 2.0f * c1 * s1;
            float c3 = c1 * c2 - s1 * s2, s3 = c1 * s2 + s1 * c2;
            bfly4(x[c], x[c + 4], x[c + 8], x[c + 12], c1, s1, c2, s2, c3, s3);
        }
    }
    // Stage R+1: twiddle base W^(4t) = T^4.
    {
        float cA = ct * ct - st * st, sA = 2.0f * ct * st;      // T^2
        float c1 = cA * cA - sA * sA, s1 = 2.0f * cA * sA;      // T^4
        float c2 = c1 * c1 - s1 * s1, s2 = 2.0f * c1 * s1;      // T^8
        float c3 = c1 * c2 - s1 * s2, s3 = c1 * s2 + s1 * c2;   // T^12
        #pragma unroll
        for (int g = 0; g < 4; ++g)
            bfly4(x[4 * g], x[4 * g + 1], x[4 * g + 2], x[4 * g + 3],
                  c1, s1, c2, s2, c3, s3);
    }

    if constexpr (!FINAL) {
        #pragma unroll
        for (int j = 0; j < 16; ++j) stz(z, PADI(i0 + (j << L2S)), x[j].x, x[j].y);
    } else {
        // Final radix-4 (stage 6, q=1): quad {base..base+3} lives in 4
        // adjacent lanes (t = tid&3) at the same reg slot. Twiddle-free.
        const int hi2 = tid & 2, hi1 = tid & 1;
        #pragma unroll
        for (int j = 0; j < 16; ++j) {
            float2 v = x[j];
            float2 p = make_float2(__shfl_xor(v.x, 2), __shfl_xor(v.y, 2));
            float2 e = hi2 ? make_float2(p.x - v.x, p.y - v.y)
                           : make_float2(v.x + p.x, v.y + p.y);
            float2 q = make_float2(__shfl_xor(e.x, 1), __shfl_xor(e.y, 1));
            float2 o;
            if (!hi2) o = hi1 ? make_float2(q.x - e.x, q.y - e.y)
                              : make_float2(e.x + q.x, e.y + q.y);
            else      o = hi1 ? make_float2(q.x - e.y, q.y + e.x)
                              : make_float2(e.x + q.y, e.y - q.x);
            stz(z, PADI(i0 + (j << 2)), o.x, o.y);
        }
    }
}

// Recover |X[k]|^2 (ortho-normalized) from the packed complex FFT result
// (bit-reversed storage).
__device__ inline float bin_power(const __half2* __restrict__ z, int k) {
    int rk  = (int)(__brev((unsigned)k)        >> (32 - LOG2M));
    int rmk = (int)(__brev((unsigned)(MPTS-k)) >> (32 - LOG2M));
    float2 a = ldz(z, PADI(rk));
    float2 b = ldz(z, PADI(rmk));
    float bx = b.x, by = -b.y;                    // conj(Z[M-k])
    float ex = 0.5f * (a.x + bx), ey = 0.5f * (a.y + by);   // Xe[k]
    float dx = a.x - bx,          dy = a.y - by;
    float ox = 0.5f * dy,         oy = -0.5f * dx;          // Xo[k] = -i/2 * d
    float ang = (-6.283185307179586f / (float)NPTS) * (float)k;
    float c, sn;
    __sincosf(ang, &sn, &c);
    float Xx = ex + ox * c - oy * sn;
    float Xy = ey + ox * sn + oy * c;
    return (Xx * Xx + Xy * Xy) * (1.0f / (float)NPTS);      // ortho: |X|^2 / N
}

__global__ __launch_bounds__(NTHR, 8) void snr_row_kernel(
        const float* __restrict__ outs,
        const float* __restrict__ targets,
        float* __restrict__ row_loss) {
    __shared__ __half2 z[ZLEN];         // 68 KiB (padded) -> 2 blocks/CU
    __shared__ float   red[NTHR / 64];

    const int b   = blockIdx.x;
    const int tid = threadIdx.x;
    const int lane = tid & 63, wave = tid >> 6;
    const float* row = outs + (size_t)b * NPTS;

    // ---- Load row, pack real pairs into complex: z[m] = x[2m] + i x[2m+1]
    // Short liveness (load -> immediate LDS store); no cross-phase registers.
    #pragma unroll
    for (int it = 0; it < (NPTS / 4) / NTHR; ++it) {
        int i = tid + it * NTHR;
        float4 v = *reinterpret_cast<const float4*>(row + 4 * i);
        stz(z, PADI(2 * i),     v.x, v.y);
        stz(z, PADI(2 * i + 1), v.z, v.w);
    }
    __syncthreads();

    // ---- DIF FFT 16384 = 16^3 * 4, natural in -> bit-reversed out.
    fused16<0, 10, false>(z, tid); __syncthreads();
    fused16<2, 6,  false>(z, tid); __syncthreads();
    fused16<4, 2,  true >(z, tid); __syncthreads();

    // ---- Band power sum over k in [MIN_IDX, MAX_IDX) = hi-blocks 4..26.
    // Dense slot space s -> (hi = 4 + s%23, m = s/23), k = hi<<8 | m:
    // ~97% lane activity; lane bits stay in k's high bits so each wave read
    // still lands in few 64-element bit-reversed chunks (~2-way aliasing).
    float local = 0.0f;
    for (int s = tid; s < 23 * 256; s += NTHR) {
        int m  = s / 23;
        int hi = 4 + (s - m * 23);
        int k  = (hi << 8) | m;
        if (k >= MIN_IDX && k < MAX_IDX) local += bin_power(z, k);
    }
    for (int off = 32; off; off >>= 1) local += __shfl_down(local, off);
    if (lane == 0) red[wave] = local;
    __syncthreads();

    if (tid == 0) {
        float S = 0.0f;
        #pragma unroll
        for (int w = 0; w < NTHR / 64; ++w) S += red[w];

        // ref_idx: argmin_k |f[k]-t|, f[k] = k*(10/16384) exact in fp32.
        float tgt = targets[b];
        double kd = (double)tgt * (16384.0 / 10.0);
        int k0 = (int)kd;                       // t>0 so trunc == floor
        const float stepf = 10.0f / 16384.0f;   // exactly representable
        float f0 = (float)k0 * stepf;           // exact products (<=24b)
        float f1 = (float)(k0 + 1) * stepf;
        float d0 = fabsf(f0 - tgt);
        float d1 = fabsf(f1 - tgt);
        int rr = (d0 <= d1) ? k0 : (k0 + 1);

        float pm1 = bin_power(z, rr - 1);
        float p0  = bin_power(z, rr);
        float pp1 = bin_power(z, rr + 1);
        float other_avg = (S - pm1 - p0 - pp1) * (1.0f / DENOMF);
        row_loss[b] = -10.0f * log10f(p0 / other_avg);
    }
}

__global__ __launch_bounds__(256) void snr_reduce_kernel(
        const float* __restrict__ row_loss, float* __restrict__ out) {
    __shared__ float red[4];
    float s = 0.0f;
    for (int i = threadIdx.x; i < BROWS; i += 256) s += row_loss[i];
    for (int off = 32; off; off >>= 1) s += __shfl_down(s, off);
    if ((threadIdx.x & 63) == 0) red[threadIdx.x >> 6] = s;
    __syncthreads();
    if (threadIdx.x == 0)
        out[0] = (red[0] + red[1] + red[2] + red[3]) * (1.0f / (float)BROWS);
}

extern "C" void kernel_launch(void* const* d_in, const int* in_sizes, int n_in,
                              void* d_out, int out_size, void* d_ws, size_t ws_size,
                              hipStream_t stream) {
    const float* outs    = (const float*)d_in[0];
    const float* targets = (const float*)d_in[1];
    float* ws  = (float*)d_ws;    // 1024 per-row losses
    float* out = (float*)d_out;

    snr_row_kernel<<<BROWS, NTHR, 0, stream>>>(outs, targets, ws);
    snr_reduce_kernel<<<1, 256, 0, stream>>>(ws, out);
}

// Round 7
// 79.594 us; speedup vs baseline: 2.4727x; 2.4727x over previous
//
#include <hip/hip_runtime.h>
#include <hip/hip_fp16.h>
#include <math.h>

// Problem constants (match reference exactly)
#define BROWS 1024
#define NPTS  32768
#define MPTS  16384          // NPTS/2 (complex FFT size via real-packing trick)
#define LOG2M 14
#define NTHR  1024
#define MIN_IDX 1092         // argmin |f - 40/60|, f[k]=k*10/16384 (exact fp32 grid)
#define MAX_IDX 6827         // argmin |f - 250/60|
#define DENOMF  5732.0f      // MAX_IDX - MIN_IDX - 3
#define W0 (-6.283185307179586f / (float)MPTS)

// LDS pad-swizzle: one element pad per 16 keeps all 4^k strides at <=3-way
// bank aliasing with 4B elements (half2): element index == bank word index.
#define PADI(i) ((i) + ((i) >> 4))
#define ZLEN    (MPTS + (MPTS >> 4))   // 17408 half2 = 68 KiB -> 2 blocks/CU

__device__ inline float2 ldz(const __half2* __restrict__ z, int i) {
    return __half22float2(z[i]);
}
__device__ inline void stz(__half2* __restrict__ z, int i, float x, float y) {
    z[i] = __floats2half2_rn(x, y);
}

// Radix-4 DIF butterfly, in-place on 4 regs; slot order (+0,+q,+2q,+3q).
// Twiddles: p1 *= (c2,s2)=W^2j, p2 *= (c1,s1)=W^j, p3 *= (c3,s3)=W^3j.
__device__ inline void bfly4(float2& p0, float2& p1, float2& p2, float2& p3,
                             float c1, float s1, float c2, float s2,
                             float c3, float s3) {
    float e0x = p0.x + p2.x, e0y = p0.y + p2.y;
    float e1x = p0.x - p2.x, e1y = p0.y - p2.y;
    float e2x = p1.x + p3.x, e2y = p1.y + p3.y;
    float e3x = p1.x - p3.x, e3y = p1.y - p3.y;
    float o1x = e0x - e2x, o1y = e0y - e2y;
    float o2x = e1x + e3y, o2y = e1y - e3x;
    float o3x = e1x - e3y, o3y = e1y + e3x;
    p0 = make_float2(e0x + e2x, e0y + e2y);
    p1 = make_float2(o1x * c2 - o1y * s2, o1x * s2 + o1y * c2);
    p2 = make_float2(o2x * c1 - o2y * s1, o2x * s1 + o2y * c1);
    p3 = make_float2(o3x * c3 - o3y * s3, o3x * s3 + o3y * c3);
}

// Fused pair of radix-4 DIF stages (global stage indices R, R+1) in registers.
// One sincos per call; other twiddles via constant rotations e^{-2pi i c/16}
// (stage R) and repeated complex squaring T^4/T^8/T^12 (stage R+1).
// FINAL additionally performs the last radix-4 stage (q=1, twiddle-free)
// across 4 adjacent lanes via shfl_xor and stores the result.
template<int R, int L2S, bool FINAL>
__device__ inline void fused16(__half2* __restrict__ z, int tid) {
    const int q2  = 1 << L2S;
    const int t   = tid & (q2 - 1);
    const int blk = tid >> L2S;
    const int i0  = (blk << (L2S + 4)) + t;

    float2 x[16];
    #pragma unroll
    for (int j = 0; j < 16; ++j) x[j] = ldz(z, PADI(i0 + (j << L2S)));

    const float A1 = W0 * (float)(1 << (2 * R));
    float ct, st;
    __sincosf(A1 * (float)t, &st, &ct);

    // Stage R: sub-butterfly c on (x[c],x[c+4],x[c+8],x[c+12]),
    // twiddle W^((c<<L2S)+t) = T * e^{-2pi i c/16}.
    {
        const float kc[4] = {1.0f, 0.9238795325f, 0.7071067812f, 0.3826834324f};
        const float ks[4] = {0.0f, -0.3826834324f, -0.7071067812f, -0.9238795325f};
        #pragma unroll
        for (int c = 0; c < 4; ++c) {
            float c1 = ct * kc[c] - st * ks[c];
            float s1 = st * kc[c] + ct * ks[c];
            float c2 = c1 * c1 - s1 * s1, s2 = 2.0f * c1 * s1;
            float c3 = c1 * c2 - s1 * s2, s3 = c1 * s2 + s1 * c2;
            bfly4(x[c], x[c + 4], x[c + 8], x[c + 12], c1, s1, c2, s2, c3, s3);
        }
    }
    // Stage R+1: twiddle base W^(4t) = T^4.
    {
        float cA = ct * ct - st * st, sA = 2.0f * ct * st;      // T^2
        float c1 = cA * cA - sA * sA, s1 = 2.0f * cA * sA;      // T^4
        float c2 = c1 * c1 - s1 * s1, s2 = 2.0f * c1 * s1;      // T^8
        float c3 = c1 * c2 - s1 * s2, s3 = c1 * s2 + s1 * c2;   // T^12
        #pragma unroll
        for (int g = 0; g < 4; ++g)
            bfly4(x[4 * g], x[4 * g + 1], x[4 * g + 2], x[4 * g + 3],
                  c1, s1, c2, s2, c3, s3);
    }

    if constexpr (!FINAL) {
        #pragma unroll
        for (int j = 0; j < 16; ++j) stz(z, PADI(i0 + (j << L2S)), x[j].x, x[j].y);
    } else {
        // Final radix-4 (stage 6, q=1): quad {base..base+3} lives in 4
        // adjacent lanes (t = tid&3) at the same reg slot. Twiddle-free.
        const int hi2 = tid & 2, hi1 = tid & 1;
        #pragma unroll
        for (int j = 0; j < 16; ++j) {
            float2 v = x[j];
            float2 p = make_float2(__shfl_xor(v.x, 2), __shfl_xor(v.y, 2));
            float2 e = hi2 ? make_float2(p.x - v.x, p.y - v.y)
                           : make_float2(v.x + p.x, v.y + p.y);
            float2 q = make_float2(__shfl_xor(e.x, 1), __shfl_xor(e.y, 1));
            float2 o;
            if (!hi2) o = hi1 ? make_float2(q.x - e.x, q.y - e.y)
                              : make_float2(e.x + q.x, e.y + q.y);
            else      o = hi1 ? make_float2(q.x - e.y, q.y + e.x)
                              : make_float2(e.x + q.y, e.y - q.x);
            stz(z, PADI(i0 + (j << 2)), o.x, o.y);
        }
    }
}

// Recover |X[k]|^2 (ortho-normalized) from the packed complex FFT result
// (bit-reversed storage).
__device__ inline float bin_power(const __half2* __restrict__ z, int k) {
    int rk  = (int)(__brev((unsigned)k)        >> (32 - LOG2M));
    int rmk = (int)(__brev((unsigned)(MPTS-k)) >> (32 - LOG2M));
    float2 a = ldz(z, PADI(rk));
    float2 b = ldz(z, PADI(rmk));
    float bx = b.x, by = -b.y;                    // conj(Z[M-k])
    float ex = 0.5f * (a.x + bx), ey = 0.5f * (a.y + by);   // Xe[k]
    float dx = a.x - bx,          dy = a.y - by;
    float ox = 0.5f * dy,         oy = -0.5f * dx;          // Xo[k] = -i/2 * d
    float ang = (-6.283185307179586f / (float)NPTS) * (float)k;
    float c, sn;
    __sincosf(ang, &sn, &c);
    float Xx = ex + ox * c - oy * sn;
    float Xy = ey + ox * sn + oy * c;
    return (Xx * Xx + Xy * Xy) * (1.0f / (float)NPTS);      // ortho: |X|^2 / N
}

// min-waves/EU = 1: do NOT constrain the allocator (R5's (.,8) forced a
// 32-VGPR target and spilled the butterfly state -> 800 MB scratch traffic).
// R4 evidence: this body naturally compiles to 64 VGPR = the exact budget
// for 8 waves/EU -> two 68 KiB blocks co-resident per CU.
__global__ __launch_bounds__(NTHR, 1) void snr_row_kernel(
        const float* __restrict__ outs,
        const float* __restrict__ targets,
        float* __restrict__ row_loss) {
    __shared__ __half2 z[ZLEN];         // 68 KiB (padded) -> 2 blocks/CU
    __shared__ float   red[NTHR / 64];

    const int b   = blockIdx.x;
    const int tid = threadIdx.x;
    const int lane = tid & 63, wave = tid >> 6;
    const float* row = outs + (size_t)b * NPTS;

    // ---- Load row, pack real pairs into complex: z[m] = x[2m] + i x[2m+1]
    // Short liveness (load -> immediate LDS store); no cross-phase registers.
    #pragma unroll
    for (int it = 0; it < (NPTS / 4) / NTHR; ++it) {
        int i = tid + it * NTHR;
        float4 v = *reinterpret_cast<const float4*>(row + 4 * i);
        stz(z, PADI(2 * i),     v.x, v.y);
        stz(z, PADI(2 * i + 1), v.z, v.w);
    }
    __syncthreads();

    // ---- DIF FFT 16384 = 16^3 * 4, natural in -> bit-reversed out.
    fused16<0, 10, false>(z, tid); __syncthreads();
    fused16<2, 6,  false>(z, tid); __syncthreads();
    fused16<4, 2,  true >(z, tid); __syncthreads();

    // ---- Band power sum over k in [MIN_IDX, MAX_IDX) = hi-blocks 4..26.
    // Dense slot space s -> (hi = 4 + s%23, m = s/23), k = hi<<8 | m:
    // ~97% lane activity; lane bits stay in k's high bits so each wave read
    // still lands in few 64-element bit-reversed chunks (~2-way aliasing).
    float local = 0.0f;
    for (int s = tid; s < 23 * 256; s += NTHR) {
        int m  = s / 23;
        int hi = 4 + (s - m * 23);
        int k  = (hi << 8) | m;
        if (k >= MIN_IDX && k < MAX_IDX) local += bin_power(z, k);
    }
    for (int off = 32; off; off >>= 1) local += __shfl_down(local, off);
    if (lane == 0) red[wave] = local;
    __syncthreads();

    if (tid == 0) {
        float S = 0.0f;
        #pragma unroll
        for (int w = 0; w < NTHR / 64; ++w) S += red[w];

        // ref_idx: argmin_k |f[k]-t|, f[k] = k*(10/16384) exact in fp32.
        float tgt = targets[b];
        double kd = (double)tgt * (16384.0 / 10.0);
        int k0 = (int)kd;                       // t>0 so trunc == floor
        const float stepf = 10.0f / 16384.0f;   // exactly representable
        float f0 = (float)k0 * stepf;           // exact products (<=24b)
        float f1 = (float)(k0 + 1) * stepf;
        float d0 = fabsf(f0 - tgt);
        float d1 = fabsf(f1 - tgt);
        int rr = (d0 <= d1) ? k0 : (k0 + 1);

        float pm1 = bin_power(z, rr - 1);
        float p0  = bin_power(z, rr);
        float pp1 = bin_power(z, rr + 1);
        float other_avg = (S - pm1 - p0 - pp1) * (1.0f / DENOMF);
        row_loss[b] = -10.0f * log10f(p0 / other_avg);
    }
}

__global__ __launch_bounds__(256) void snr_reduce_kernel(
        const float* __restrict__ row_loss, float* __restrict__ out) {
    __shared__ float red[4];
    float s = 0.0f;
    for (int i = threadIdx.x; i < BROWS; i += 256) s += row_loss[i];
    for (int off = 32; off; off >>= 1) s += __shfl_down(s, off);
    if ((threadIdx.x & 63) == 0) red[threadIdx.x >> 6] = s;
    __syncthreads();
    if (threadIdx.x == 0)
        out[0] = (red[0] + red[1] + red[2] + red[3]) * (1.0f / (float)BROWS);
}

extern "C" void kernel_launch(void* const* d_in, const int* in_sizes, int n_in,
                              void* d_out, int out_size, void* d_ws, size_t ws_size,
                              hipStream_t stream) {
    const float* outs    = (const float*)d_in[0];
    const float* targets = (const float*)d_in[1];
    float* ws  = (float*)d_ws;    // 1024 per-row losses
    float* out = (float*)d_out;

    snr_row_kernel<<<BROWS, NTHR, 0, stream>>>(outs, targets, ws);
    snr_reduce_kernel<<<1, 256, 0, stream>>>(ws, out);
}

// Round 8
// 61.867 us; speedup vs baseline: 3.1812x; 1.2865x over previous
//
#include <hip/hip_runtime.h>
#include <hip/hip_fp16.h>
#include <math.h>

// Problem constants (match reference exactly)
#define BROWS 1024
#define NPTS  32768
#define MPTS  16384          // NPTS/2 (complex FFT size via real-packing trick)
#define LOG2M 14
#define NTHR  512            // 8 waves; 2 independent blocks co-resident per CU
#define MIN_IDX 1092         // argmin |f - 40/60|, f[k]=k*10/16384 (exact fp32 grid)
#define MAX_IDX 6827         // argmin |f - 250/60|
#define DENOMF  5732.0f      // MAX_IDX - MIN_IDX - 3
#define W0 (-6.283185307179586f / (float)MPTS)

// LDS pad-swizzle: one element pad per 16 keeps all 4^k strides near the
// bank floor with 4B elements (half2): element index == bank word index.
#define PADI(i) ((i) + ((i) >> 4))
#define ZLEN    (MPTS + (MPTS >> 4))   // 17408 half2 = 68 KiB -> 2 blocks/CU

__device__ inline float2 ldz(const __half2* __restrict__ z, int i) {
    return __half22float2(z[i]);
}
__device__ inline void stz(__half2* __restrict__ z, int i, float x, float y) {
    z[i] = __floats2half2_rn(x, y);
}

// Radix-4 DIF butterfly, in-place on 4 regs; slot order (+0,+q,+2q,+3q).
// Twiddles: p1 *= (c2,s2)=W^2j, p2 *= (c1,s1)=W^j, p3 *= (c3,s3)=W^3j.
__device__ inline void bfly4(float2& p0, float2& p1, float2& p2, float2& p3,
                             float c1, float s1, float c2, float s2,
                             float c3, float s3) {
    float e0x = p0.x + p2.x, e0y = p0.y + p2.y;
    float e1x = p0.x - p2.x, e1y = p0.y - p2.y;
    float e2x = p1.x + p3.x, e2y = p1.y + p3.y;
    float e3x = p1.x - p3.x, e3y = p1.y - p3.y;
    float o1x = e0x - e2x, o1y = e0y - e2y;
    float o2x = e1x + e3y, o2y = e1y - e3x;
    float o3x = e1x - e3y, o3y = e1y + e3x;
    p0 = make_float2(e0x + e2x, e0y + e2y);
    p1 = make_float2(o1x * c2 - o1y * s2, o1x * s2 + o1y * c2);
    p2 = make_float2(o2x * c1 - o2y * s1, o2x * s1 + o2y * c1);
    p3 = make_float2(o3x * c3 - o3y * s3, o3x * s3 + o3y * c3);
}

// Register radix-16 core = fused pair of radix-4 DIF stages (R, R+1).
// Requires 4^R * 2^L2S == 1024 so the stage-R offset rotations are the
// constant e^{-2pi i c/16}. One sincos; the rest by squaring/products.
template<int R, int L2S>
__device__ inline void radix16_core(float2 x[16], int t) {
    const float A1 = W0 * (float)(1 << (2 * R));
    float ct, st;
    __sincosf(A1 * (float)t, &st, &ct);

    // Stage R: butterfly c on (x[c],x[c+4],x[c+8],x[c+12]),
    // twiddle W^((c<<L2S)+t) = T * e^{-2pi i c/16}.
    {
        const float kc[4] = {1.0f, 0.9238795325f, 0.7071067812f, 0.3826834324f};
        const float ks[4] = {0.0f, -0.3826834324f, -0.7071067812f, -0.9238795325f};
        #pragma unroll
        for (int c = 0; c < 4; ++c) {
            float c1 = ct * kc[c] - st * ks[c];
            float s1 = st * kc[c] + ct * ks[c];
            float c2 = c1 * c1 - s1 * s1, s2 = 2.0f * c1 * s1;
            float c3 = c1 * c2 - s1 * s2, s3 = c1 * s2 + s1 * c2;
            bfly4(x[c], x[c + 4], x[c + 8], x[c + 12], c1, s1, c2, s2, c3, s3);
        }
    }
    // Stage R+1: twiddle base W^(4t) = T^4 (via T^2), then T^8, T^12.
    {
        float cA = ct * ct - st * st, sA = 2.0f * ct * st;      // T^2
        float c1 = cA * cA - sA * sA, s1 = 2.0f * cA * sA;      // T^4
        float c2 = c1 * c1 - s1 * s1, s2 = 2.0f * c1 * s1;      // T^8
        float c3 = c1 * c2 - s1 * s2, s3 = c1 * s2 + s1 * c2;   // T^12
        #pragma unroll
        for (int g = 0; g < 4; ++g)
            bfly4(x[4 * g], x[4 * g + 1], x[4 * g + 2], x[4 * g + 3],
                  c1, s1, c2, s2, c3, s3);
    }
}

// Stage 0 (R=0, L2S=10): inputs read DIRECTLY from global (coalesced 8B/lane,
// natural order: element m = (row[2m], row[2m+1])), outputs to LDS.
// Saves the pack->LDS->barrier->reload round-trip and one fp16 quantization.
__device__ inline void stage0_global(__half2* __restrict__ z,
                                     const float* __restrict__ row, int idx) {
    const float2* rp = reinterpret_cast<const float2*>(row);
    float2 x[16];
    #pragma unroll
    for (int j = 0; j < 16; ++j) x[j] = rp[idx + (j << 10)];
    radix16_core<0, 10>(x, idx);        // blk==0, t==idx for idx<1024
    #pragma unroll
    for (int j = 0; j < 16; ++j) stz(z, PADI(idx + (j << 10)), x[j].x, x[j].y);
}

// Stage 1 (R=2, L2S=6): LDS -> regs -> LDS.
__device__ inline void stage1(__half2* __restrict__ z, int idx) {
    const int t = idx & 63, blk = idx >> 6;
    const int i0 = (blk << 10) + t;
    float2 x[16];
    #pragma unroll
    for (int j = 0; j < 16; ++j) x[j] = ldz(z, PADI(i0 + (j << 6)));
    radix16_core<2, 6>(x, t);
    #pragma unroll
    for (int j = 0; j < 16; ++j) stz(z, PADI(i0 + (j << 6)), x[j].x, x[j].y);
}

// Stage 2 (R=4, L2S=2) + final radix-4 (q=1, twiddle-free) across 4 adjacent
// lanes via shfl_xor; stores the bit-reversed-order result.
__device__ inline void stage2_final(__half2* __restrict__ z, int idx) {
    const int t = idx & 3, blk = idx >> 2;
    const int i0 = (blk << 6) + t;
    float2 x[16];
    #pragma unroll
    for (int j = 0; j < 16; ++j) x[j] = ldz(z, PADI(i0 + (j << 2)));
    radix16_core<4, 2>(x, t);

    const int hi2 = idx & 2, hi1 = idx & 1;   // == tid&2, tid&1 (chunk +512)
    #pragma unroll
    for (int j = 0; j < 16; ++j) {
        float2 v = x[j];
        float2 p = make_float2(__shfl_xor(v.x, 2), __shfl_xor(v.y, 2));
        float2 e = hi2 ? make_float2(p.x - v.x, p.y - v.y)
                       : make_float2(v.x + p.x, v.y + p.y);
        float2 q = make_float2(__shfl_xor(e.x, 1), __shfl_xor(e.y, 1));
        float2 o;
        if (!hi2) o = hi1 ? make_float2(q.x - e.x, q.y - e.y)
                          : make_float2(e.x + q.x, e.y + q.y);
        else      o = hi1 ? make_float2(q.x - e.y, q.y + e.x)
                          : make_float2(e.x + q.y, e.y - q.x);
        stz(z, PADI(i0 + (j << 2)), o.x, o.y);
    }
}

// Recover |X[k]|^2 (ortho-normalized) from the packed complex FFT result
// (bit-reversed storage).
__device__ inline float bin_power(const __half2* __restrict__ z, int k) {
    int rk  = (int)(__brev((unsigned)k)        >> (32 - LOG2M));
    int rmk = (int)(__brev((unsigned)(MPTS-k)) >> (32 - LOG2M));
    float2 a = ldz(z, PADI(rk));
    float2 b = ldz(z, PADI(rmk));
    float bx = b.x, by = -b.y;                    // conj(Z[M-k])
    float ex = 0.5f * (a.x + bx), ey = 0.5f * (a.y + by);   // Xe[k]
    float dx = a.x - bx,          dy = a.y - by;
    float ox = 0.5f * dy,         oy = -0.5f * dx;          // Xo[k] = -i/2 * d
    float ang = (-6.283185307179586f / (float)NPTS) * (float)k;
    float c, sn;
    __sincosf(ang, &sn, &c);
    float Xx = ex + ox * c - oy * sn;
    float Xy = ey + ox * sn + oy * c;
    return (Xx * Xx + Xy * Xy) * (1.0f / (float)NPTS);      // ortho: |X|^2 / N
}

// launch_bounds (512, 4): compiler VGPR target 64 = the proven-achievable
// body size (R6). Residency law from R5/R6: waves/SIMD ~ floor(256/VGPR);
// at 64 VGPR -> 4/SIMD -> two 8-wave blocks co-resident (independent, so one
// block's compute fills the other's barrier stalls). DO NOT raise min-waves
// (R5: target 32 -> full spill) or drop it (natural interleave could exceed
// 64 -> single block).
__global__ __launch_bounds__(NTHR, 4) void snr_row_kernel(
        const float* __restrict__ outs,
        const float* __restrict__ targets,
        float* __restrict__ row_loss) {
    __shared__ __half2 z[ZLEN];         // 68 KiB (padded) -> 2 blocks/CU
    __shared__ float   red[NTHR / 64];

    const int b   = blockIdx.x;
    const int tid = threadIdx.x;
    const int lane = tid & 63, wave = tid >> 6;
    const float* row = outs + (size_t)b * NPTS;

    // ---- DIF FFT 16384 = 16^3 * 4: stage0 straight from global; 2 chunks
    // per thread per stage (unroll 1: one chunk's registers live at a time).
    #pragma unroll 1
    for (int c = 0; c < 2; ++c) stage0_global(z, row, tid + c * NTHR);
    __syncthreads();
    #pragma unroll 1
    for (int c = 0; c < 2; ++c) stage1(z, tid + c * NTHR);
    __syncthreads();
    #pragma unroll 1
    for (int c = 0; c < 2; ++c) stage2_final(z, tid + c * NTHR);
    __syncthreads();

    // ---- Band power sum over k in [MIN_IDX, MAX_IDX) = hi-blocks 4..26.
    // Dense slot space s -> (hi = 4 + s%23, m = s/23), k = hi<<8 | m:
    // ~97% lane activity; lane bits stay in k's high bits so each wave read
    // lands in few 64-element bit-reversed chunks (low-way aliasing).
    float local = 0.0f;
    #pragma unroll 2
    for (int s = tid; s < 23 * 256; s += NTHR) {
        int m  = s / 23;
        int hi = 4 + (s - m * 23);
        int k  = (hi << 8) | m;
        if (k >= MIN_IDX && k < MAX_IDX) local += bin_power(z, k);
    }
    for (int off = 32; off; off >>= 1) local += __shfl_down(local, off);
    if (lane == 0) red[wave] = local;
    __syncthreads();

    if (tid == 0) {
        float S = 0.0f;
        #pragma unroll
        for (int w = 0; w < NTHR / 64; ++w) S += red[w];

        // ref_idx: argmin_k |f[k]-t|, f[k] = k*(10/16384) exact in fp32.
        float tgt = targets[b];
        double kd = (double)tgt * (16384.0 / 10.0);
        int k0 = (int)kd;                       // t>0 so trunc == floor
        const float stepf = 10.0f / 16384.0f;   // exactly representable
        float f0 = (float)k0 * stepf;           // exact products (<=24b)
        float f1 = (float)(k0 + 1) * stepf;
        float d0 = fabsf(f0 - tgt);
        float d1 = fabsf(f1 - tgt);
        int rr = (d0 <= d1) ? k0 : (k0 + 1);

        float pm1 = bin_power(z, rr - 1);
        float p0  = bin_power(z, rr);
        float pp1 = bin_power(z, rr + 1);
        float other_avg = (S - pm1 - p0 - pp1) * (1.0f / DENOMF);
        row_loss[b] = -10.0f * log10f(p0 / other_avg);
    }
}

__global__ __launch_bounds__(256) void snr_reduce_kernel(
        const float* __restrict__ row_loss, float* __restrict__ out) {
    __shared__ float red[4];
    float s = 0.0f;
    for (int i = threadIdx.x; i < BROWS; i += 256) s += row_loss[i];
    for (int off = 32; off; off >>= 1) s += __shfl_down(s, off);
    if ((threadIdx.x & 63) == 0) red[threadIdx.x >> 6] = s;
    __syncthreads();
    if (threadIdx.x == 0)
        out[0] = (red[0] + red[1] + red[2] + red[3]) * (1.0f / (float)BROWS);
}

extern "C" void kernel_launch(void* const* d_in, const int* in_sizes, int n_in,
                              void* d_out, int out_size, void* d_ws, size_t ws_size,
                              hipStream_t stream) {
    const float* outs    = (const float*)d_in[0];
    const float* targets = (const float*)d_in[1];
    float* ws  = (float*)d_ws;    // 1024 per-row losses
    float* out = (float*)d_out;

    snr_row_kernel<<<BROWS, NTHR, 0, stream>>>(outs, targets, ws);
    snr_reduce_kernel<<<1, 256, 0, stream>>>(ws, out);
}